// Round 1
// baseline (133.380 us; speedup 1.0000x reference)
//
#include <hip/hip_runtime.h>
#include <hip/hip_bf16.h>
#include <stdint.h>

using bf16 = __hip_bfloat16;
typedef __attribute__((ext_vector_type(8))) short bf16x8;   // 8 bf16 = 4 VGPRs
typedef __attribute__((ext_vector_type(4))) float f32x4;

// ---------------------------------------------------------------------------
// async global->LDS, 16B per lane (global_load_lds_dwordx4).
// LDS dest is wave-uniform base + lane*16; global src is per-lane.
// ---------------------------------------------------------------------------
__device__ __forceinline__ void async16(const void* g, void* lds) {
  __builtin_amdgcn_global_load_lds(
      (const __attribute__((address_space(1))) void*)g,
      (__attribute__((address_space(3))) void*)lds, 16, 0, 0);
}

// ---------------------------------------------------------------------------
// Build Kron-expanded DOWN weight, TRANSPOSED, bf16:  wdT[n][k], n in [0,512), k in [0,2048)
// Wd[k = p*512+q][n = r*128+s] = sum_i phm[i,p,r] * W_down[i,q,s]
// ---------------------------------------------------------------------------
__global__ void build_wdT(const float* __restrict__ phm,
                          const float* __restrict__ Wd,
                          bf16* __restrict__ out) {
  int idx = blockIdx.x * 256 + threadIdx.x;          // 512*2048
  if (idx >= 512 * 2048) return;
  int n = idx >> 11;          // row of wdT (col of Wd)
  int k = idx & 2047;         // col of wdT (row of Wd)
  int r = n >> 7, s = n & 127;
  int p = k >> 9, q = k & 511;
  float v = 0.f;
#pragma unroll
  for (int i = 0; i < 4; ++i)
    v += phm[i * 16 + p * 4 + r] * Wd[i * 65536 + q * 128 + s];
  out[idx] = (bf16)v;
}

// ---------------------------------------------------------------------------
// Build Kron-expanded UP weight, TRANSPOSED, bf16: wuT[d][b], d in [0,2048), b in [0,512)
// Wu[b = p*128+q][d = r*512+s] = sum_i phm[i,p,r] * W_up[i,q,s]
// ---------------------------------------------------------------------------
__global__ void build_wuT(const float* __restrict__ phm,
                          const float* __restrict__ Wu,
                          bf16* __restrict__ out) {
  int idx = blockIdx.x * 256 + threadIdx.x;          // 2048*512
  if (idx >= 2048 * 512) return;
  int d = idx >> 9;           // row of wuT
  int b = idx & 511;          // col of wuT
  int r = d >> 9, s = d & 511;
  int p = b >> 7, q = b & 127;
  float v = 0.f;
#pragma unroll
  for (int i = 0; i < 4; ++i)
    v += phm[i * 16 + p * 4 + r] * Wu[i * 65536 + q * 512 + s];
  out[idx] = (bf16)v;
}

// ---------------------------------------------------------------------------
// x (f32) -> bf16, vectorized float4 -> ushort4
// ---------------------------------------------------------------------------
__global__ void cast_f32_bf16(const float* __restrict__ in,
                              bf16* __restrict__ out, int n4) {
  int i = blockIdx.x * 256 + threadIdx.x;
  if (i >= n4) return;
  float4 v = reinterpret_cast<const float4*>(in)[i];
  ushort4 o;
  o.x = __bfloat16_as_ushort(__float2bfloat16(v.x));
  o.y = __bfloat16_as_ushort(__float2bfloat16(v.y));
  o.z = __bfloat16_as_ushort(__float2bfloat16(v.z));
  o.w = __bfloat16_as_ushort(__float2bfloat16(v.w));
  reinterpret_cast<ushort4*>(out)[i] = o;
}

// ---------------------------------------------------------------------------
// C = A[M][K] * Bt[N][K]^T (+bias, EPI=0: relu -> bf16 out ; EPI=1: -> f32 out)
// 128x128 tile, BK=32, 4 waves, 4x4 16x16x32 fragments per wave (m97 structure)
// ---------------------------------------------------------------------------
template <int EPI>
__global__ __launch_bounds__(256)
void gemm_bt(const bf16* __restrict__ A, const bf16* __restrict__ Bt,
             const float* __restrict__ bias, void* __restrict__ Cout,
             int M, int N, int K) {
  constexpr int BM = 128, BN = 128, BK = 32;
  __shared__ bf16 Ash[BM * BK];   // 8 KB
  __shared__ bf16 Bsh[BN * BK];   // 8 KB

  const int tid  = threadIdx.x;
  const int lane = tid & 63;
  const int wave = tid >> 6;
  const int wm = (wave >> 1) * 64;     // wave's row offset within tile
  const int wn = (wave & 1) * 64;      // wave's col offset within tile
  const int bm = blockIdx.x * BM;
  const int bn = blockIdx.y * BN;

  const int rl = lane & 15;            // row-in-fragment
  const int kq = (lane >> 4) * 8;      // k-offset of this lane's 8 elements

  f32x4 acc[4][4] = {};

  for (int k0 = 0; k0 < K; k0 += BK) {
    __syncthreads();   // protect LDS from previous iteration's readers
#pragma unroll
    for (int is = 0; is < 2; ++is) {
      int e = (is * 256 + tid) * 8;    // bf16 element index in A tile
      int r = e >> 5, c = e & 31;
      async16(A + (size_t)(bm + r) * K + k0 + c, Ash + e);
    }
#pragma unroll
    for (int is = 0; is < 2; ++is) {
      int e = (is * 256 + tid) * 8;
      int r = e >> 5, c = e & 31;
      async16(Bt + (size_t)(bn + r) * K + k0 + c, Bsh + e);
    }
    __syncthreads();   // compiler drains vmcnt(0) before s_barrier

    bf16x8 af[4], bfr[4];
#pragma unroll
    for (int m = 0; m < 4; ++m)
      af[m] = *(const bf16x8*)(Ash + (wm + m * 16 + rl) * BK + kq);
#pragma unroll
    for (int n = 0; n < 4; ++n)
      bfr[n] = *(const bf16x8*)(Bsh + (wn + n * 16 + rl) * BK + kq);

#pragma unroll
    for (int m = 0; m < 4; ++m)
#pragma unroll
      for (int n = 0; n < 4; ++n)
        acc[m][n] = __builtin_amdgcn_mfma_f32_16x16x32_bf16(af[m], bfr[n],
                                                            acc[m][n], 0, 0, 0);
  }

  // Epilogue. C/D layout (verified m89): col = lane&15, row = (lane>>4)*4 + j
  const int rq = (lane >> 4) * 4;
#pragma unroll
  for (int n = 0; n < 4; ++n) {
    int gc = bn + wn + n * 16 + rl;
    float bv = bias[gc];
#pragma unroll
    for (int m = 0; m < 4; ++m) {
      int gr0 = bm + wm + m * 16 + rq;
#pragma unroll
      for (int j = 0; j < 4; ++j) {
        float v = acc[m][n][j] + bv;
        if constexpr (EPI == 0) {
          v = v > 0.f ? v : 0.f;
          ((bf16*)Cout)[(size_t)(gr0 + j) * N + gc] = __float2bfloat16(v);
        } else {
          ((float*)Cout)[(size_t)(gr0 + j) * N + gc] = v;
        }
      }
    }
  }
}

// ---------------------------------------------------------------------------
extern "C" void kernel_launch(void* const* d_in, const int* in_sizes, int n_in,
                              void* d_out, int out_size, void* d_ws, size_t ws_size,
                              hipStream_t stream) {
  const float* x      = (const float*)d_in[0];   // [8192,2048]
  const float* phm    = (const float*)d_in[1];   // [4,4,4]
  const float* W_down = (const float*)d_in[2];   // [4,512,128]
  const float* b_down = (const float*)d_in[3];   // [512]
  const float* W_up   = (const float*)d_in[4];   // [4,128,512]
  const float* b_up   = (const float*)d_in[5];   // [2048]
  float* out = (float*)d_out;                    // [8192,2048] f32

  const int T = 8192, D = 2048, B = 512;

  char* ws = (char*)d_ws;
  bf16* xb  = (bf16*)(ws);                                  // 32 MB
  bf16* wdT = (bf16*)(ws + (size_t)32 * 1024 * 1024);       //  2 MB  [512][2048]
  bf16* wuT = (bf16*)(ws + (size_t)34 * 1024 * 1024);       //  2 MB  [2048][512]
  bf16* z   = (bf16*)(ws + (size_t)36 * 1024 * 1024);       //  8 MB  [8192][512]

  // prep
  cast_f32_bf16<<<dim3((T * D / 4 + 255) / 256), dim3(256), 0, stream>>>(x, xb, T * D / 4);
  build_wdT<<<dim3((B * D + 255) / 256), dim3(256), 0, stream>>>(phm, W_down, wdT);
  build_wuT<<<dim3((D * B + 255) / 256), dim3(256), 0, stream>>>(phm, W_up, wuT);

  // z = relu(x @ Wd + b_down)   [8192,512] bf16
  gemm_bt<0><<<dim3(T / 128, B / 128), dim3(256), 0, stream>>>(xb, wdT, b_down, z, T, B, D);
  // out = z @ Wu + b_up         [8192,2048] f32
  gemm_bt<1><<<dim3(T / 128, D / 128), dim3(256), 0, stream>>>(z, wuT, b_up, out, T, D, B);
}

// Round 2
// 128.359 us; speedup vs baseline: 1.0391x; 1.0391x over previous
//
#include <hip/hip_runtime.h>
#include <hip/hip_bf16.h>
#include <stdint.h>

using bf16 = __hip_bfloat16;
typedef __attribute__((ext_vector_type(8))) short bf16x8;   // 8 bf16 = 4 VGPRs
typedef __attribute__((ext_vector_type(4))) float f32x4;

// ---------------------------------------------------------------------------
// async global->LDS, 16B per lane (global_load_lds_dwordx4).
// LDS dest is wave-uniform base + lane*16; global src is per-lane.
// ---------------------------------------------------------------------------
__device__ __forceinline__ void async16(const void* g, void* lds) {
  __builtin_amdgcn_global_load_lds(
      (const __attribute__((address_space(1))) void*)g,
      (__attribute__((address_space(3))) void*)lds, 16, 0, 0);
}

// ---------------------------------------------------------------------------
// Build Kron-expanded DOWN weight, TRANSPOSED, bf16:  wdT[n][k]
// ---------------------------------------------------------------------------
__global__ void build_wdT(const float* __restrict__ phm,
                          const float* __restrict__ Wd,
                          bf16* __restrict__ out) {
  int idx = blockIdx.x * 256 + threadIdx.x;          // 512*2048
  if (idx >= 512 * 2048) return;
  int n = idx >> 11;
  int k = idx & 2047;
  int r = n >> 7, s = n & 127;
  int p = k >> 9, q = k & 511;
  float v = 0.f;
#pragma unroll
  for (int i = 0; i < 4; ++i)
    v += phm[i * 16 + p * 4 + r] * Wd[i * 65536 + q * 128 + s];
  out[idx] = (bf16)v;
}

// ---------------------------------------------------------------------------
// Build Kron-expanded UP weight, TRANSPOSED, bf16: wuT[d][b]
// ---------------------------------------------------------------------------
__global__ void build_wuT(const float* __restrict__ phm,
                          const float* __restrict__ Wu,
                          bf16* __restrict__ out) {
  int idx = blockIdx.x * 256 + threadIdx.x;          // 2048*512
  if (idx >= 2048 * 512) return;
  int d = idx >> 9;
  int b = idx & 511;
  int r = d >> 9, s = d & 511;
  int p = b >> 7, q = b & 127;
  float v = 0.f;
#pragma unroll
  for (int i = 0; i < 4; ++i)
    v += phm[i * 16 + p * 4 + r] * Wu[i * 65536 + q * 512 + s];
  out[idx] = (bf16)v;
}

// ---------------------------------------------------------------------------
// x (f32) -> bf16, vectorized float4 -> ushort4
// ---------------------------------------------------------------------------
__global__ void cast_f32_bf16(const float* __restrict__ in,
                              bf16* __restrict__ out, int n4) {
  int i = blockIdx.x * 256 + threadIdx.x;
  if (i >= n4) return;
  float4 v = reinterpret_cast<const float4*>(in)[i];
  ushort4 o;
  o.x = __bfloat16_as_ushort(__float2bfloat16(v.x));
  o.y = __bfloat16_as_ushort(__float2bfloat16(v.y));
  o.z = __bfloat16_as_ushort(__float2bfloat16(v.z));
  o.w = __bfloat16_as_ushort(__float2bfloat16(v.w));
  reinterpret_cast<ushort4*>(out)[i] = o;
}

// ---------------------------------------------------------------------------
// C = A[M][K] * Bt[N][K]^T (+bias). EPI=0: relu -> bf16 out ; EPI=1: -> f32 out
// 128x128 tile, BK=32, 4 waves, 4x4 16x16x32 fragments per wave.
// Double-buffered LDS with prefetch-before-compute (single barrier/iter).
// 16B-slot XOR swizzle (slot ^= row&3): pre-swizzled global source, linear
// LDS dest (global_load_lds requirement), swizzled ds_read. 8-way -> 4-way.
// ---------------------------------------------------------------------------
template <int EPI>
__global__ __launch_bounds__(256)
void gemm_bt(const bf16* __restrict__ A, const bf16* __restrict__ Bt,
             const float* __restrict__ bias, void* __restrict__ Cout,
             int M, int N, int K) {
  constexpr int BM = 128, BN = 128, BK = 32;
  __shared__ bf16 Ash[2][BM * BK];   // 2 x 8 KB
  __shared__ bf16 Bsh[2][BN * BK];   // 2 x 8 KB

  const int tid  = threadIdx.x;
  const int lane = tid & 63;
  const int wave = tid >> 6;
  const int wm = (wave >> 1) * 64;     // wave's row offset within tile
  const int wn = (wave & 1) * 64;      // wave's col offset within tile
  const int bm = blockIdx.x * BM;
  const int bn = blockIdx.y * BN;

  const int rl = lane & 15;            // row-in-fragment
  const int sw = lane >> 4;            // k-slot (8 elements = 16B each)

  f32x4 acc[4][4] = {};

  // staging: idx in [0,512) covers 128 rows x 4 slots of 16B
  // LDS dest linear (idx*16B); global source slot pre-swizzled by row&3.
#define STAGE(buf, kk)                                                        \
  {                                                                           \
    _Pragma("unroll")                                                         \
    for (int is = 0; is < 2; ++is) {                                          \
      int idx = is * 256 + tid;                                               \
      int r = idx >> 2, s = idx & 3;                                          \
      async16(A + (size_t)(bm + r) * K + (kk) + ((s ^ (r & 3)) * 8),          \
              &Ash[buf][idx * 8]);                                            \
    }                                                                         \
    _Pragma("unroll")                                                         \
    for (int is = 0; is < 2; ++is) {                                          \
      int idx = is * 256 + tid;                                               \
      int r = idx >> 2, s = idx & 3;                                          \
      async16(Bt + (size_t)(bn + r) * K + (kk) + ((s ^ (r & 3)) * 8),         \
              &Bsh[buf][idx * 8]);                                            \
    }                                                                         \
  }

  const int nt = K / BK;

  STAGE(0, 0);
  __syncthreads();   // drains vmcnt(0) before s_barrier

  for (int t = 0; t < nt; ++t) {
    const int cur = t & 1;
    if (t + 1 < nt) STAGE(cur ^ 1, (t + 1) * BK);   // prefetch next tile

    bf16x8 af[4], bfr[4];
#pragma unroll
    for (int m = 0; m < 4; ++m) {
      int rr = wm + m * 16 + rl;
      af[m] = *(const bf16x8*)(&Ash[cur][rr * BK + ((sw ^ (rl & 3)) * 8)]);
    }
#pragma unroll
    for (int n = 0; n < 4; ++n) {
      int rr = wn + n * 16 + rl;
      bfr[n] = *(const bf16x8*)(&Bsh[cur][rr * BK + ((sw ^ (rl & 3)) * 8)]);
    }

    __builtin_amdgcn_s_setprio(1);
#pragma unroll
    for (int m = 0; m < 4; ++m)
#pragma unroll
      for (int n = 0; n < 4; ++n)
        acc[m][n] = __builtin_amdgcn_mfma_f32_16x16x32_bf16(af[m], bfr[n],
                                                            acc[m][n], 0, 0, 0);
    __builtin_amdgcn_s_setprio(0);

    __syncthreads();   // next tile staged (vmcnt drained) + all reads done
  }
#undef STAGE

  // Epilogue. C/D layout (verified m89): col = lane&15, row = (lane>>4)*4 + j
  const int rq = sw * 4;
#pragma unroll
  for (int n = 0; n < 4; ++n) {
    int gc = bn + wn + n * 16 + rl;
    float bv = bias[gc];
#pragma unroll
    for (int m = 0; m < 4; ++m) {
      int gr0 = bm + wm + m * 16 + rq;
#pragma unroll
      for (int j = 0; j < 4; ++j) {
        float v = acc[m][n][j] + bv;
        if constexpr (EPI == 0) {
          v = v > 0.f ? v : 0.f;
          ((bf16*)Cout)[(size_t)(gr0 + j) * N + gc] = __float2bfloat16(v);
        } else {
          ((float*)Cout)[(size_t)(gr0 + j) * N + gc] = v;
        }
      }
    }
  }
}

// ---------------------------------------------------------------------------
extern "C" void kernel_launch(void* const* d_in, const int* in_sizes, int n_in,
                              void* d_out, int out_size, void* d_ws, size_t ws_size,
                              hipStream_t stream) {
  const float* x      = (const float*)d_in[0];   // [8192,2048]
  const float* phm    = (const float*)d_in[1];   // [4,4,4]
  const float* W_down = (const float*)d_in[2];   // [4,512,128]
  const float* b_down = (const float*)d_in[3];   // [512]
  const float* W_up   = (const float*)d_in[4];   // [4,128,512]
  const float* b_up   = (const float*)d_in[5];   // [2048]
  float* out = (float*)d_out;                    // [8192,2048] f32

  const int T = 8192, D = 2048, B = 512;

  char* ws = (char*)d_ws;
  bf16* xb  = (bf16*)(ws);                                  // 32 MB
  bf16* wdT = (bf16*)(ws + (size_t)32 * 1024 * 1024);       //  2 MB  [512][2048]
  bf16* wuT = (bf16*)(ws + (size_t)34 * 1024 * 1024);       //  2 MB  [2048][512]
  bf16* z   = (bf16*)(ws + (size_t)36 * 1024 * 1024);       //  8 MB  [8192][512]

  // prep
  cast_f32_bf16<<<dim3((T * D / 4 + 255) / 256), dim3(256), 0, stream>>>(x, xb, T * D / 4);
  build_wdT<<<dim3((B * D + 255) / 256), dim3(256), 0, stream>>>(phm, W_down, wdT);
  build_wuT<<<dim3((D * B + 255) / 256), dim3(256), 0, stream>>>(phm, W_up, wuT);

  // z = relu(x @ Wd + b_down)   [8192,512] bf16
  gemm_bt<0><<<dim3(T / 128, B / 128), dim3(256), 0, stream>>>(xb, wdT, b_down, z, T, B, D);
  // out = z @ Wu + b_up         [8192,2048] f32
  gemm_bt<1><<<dim3(T / 128, D / 128), dim3(256), 0, stream>>>(z, wuT, b_up, out, T, D, B);
}